// Round 2
// baseline (594.455 us; speedup 1.0000x reference)
//
#include <hip/hip_runtime.h>

#define Bn 8
#define CINn 64
#define COUTn 64
#define Hn 128
#define Wn 128
#define KKn 9

// ---------------------------------------------------------------------------
// Kernel A2: transpose w_dcn (COUT, CIN, 3,3) -> wt[k][c][o] for coalesced use
// ---------------------------------------------------------------------------
__global__ void wdcn_transpose(const float* __restrict__ w_dcn, float* __restrict__ wt) {
    int i = blockIdx.x * 256 + threadIdx.x;          // 36864 total
    if (i >= COUTn * CINn * KKn) return;
    int o = i & 63;
    int c = (i >> 6) & 63;
    int k = i >> 12;
    wt[i] = w_dcn[(o * CINn + c) * KKn + k];
}

// ---------------------------------------------------------------------------
// Kernel A: offset conv.  off[b,ch,h,w] = b_off[ch] + sum_{c,tap} x*w_off
// w_off staged in LDS as [c][tap][ch pad 28] -> all reads are lane-broadcast.
// Each thread computes 2 spatial positions (amortizes LDS w reads).
// ---------------------------------------------------------------------------
__launch_bounds__(256)
__global__ void offconv(const float* __restrict__ x, const float* __restrict__ w_off,
                        const float* __restrict__ b_off, float* __restrict__ off) {
    __shared__ float lw[CINn * KKn * 28];            // 64*9*28*4 = 64512 B
    for (int e = threadIdx.x; e < 27 * CINn * KKn; e += 256) {
        // source linear: e = (ch*64 + c)*9 + tap
        int tap = e % 9;
        int c   = (e / 9) & 63;
        int ch  = e / 576;
        lw[(c * 9 + tap) * 28 + ch] = w_off[e];
    }
    __syncthreads();

    const int t    = threadIdx.x;
    const int base = blockIdx.x * 512;
    const int p0   = base + t;
    const int p1   = base + 256 + t;
    const int b    = p0 >> 14;                       // same b for whole block (512 | 16384)
    const int h0 = (p0 >> 7) & 127, w0 = p0 & 127;
    const int h1 = (p1 >> 7) & 127, w1 = p1 & 127;

    float acc[2][27];
#pragma unroll
    for (int ch = 0; ch < 27; ++ch) {
        float bv = b_off[ch];
        acc[0][ch] = bv;
        acc[1][ch] = bv;
    }

    for (int c = 0; c < CINn; ++c) {
        const float* xc = x + (((long)b * CINn + c) << 14);
        float xv0[9], xv1[9];
#pragma unroll
        for (int di = 0; di < 3; ++di) {
#pragma unroll
            for (int dj = 0; dj < 3; ++dj) {
                int y = h0 + di - 1, xx = w0 + dj - 1;
                xv0[di * 3 + dj] = (y >= 0 && y < Hn && xx >= 0 && xx < Wn) ? xc[(y << 7) + xx] : 0.f;
                y = h1 + di - 1; xx = w1 + dj - 1;
                xv1[di * 3 + dj] = (y >= 0 && y < Hn && xx >= 0 && xx < Wn) ? xc[(y << 7) + xx] : 0.f;
            }
        }
#pragma unroll
        for (int tap = 0; tap < 9; ++tap) {
            const float4* wp = (const float4*)&lw[(c * 9 + tap) * 28];
            float4 wv[7];
#pragma unroll
            for (int q = 0; q < 7; ++q) wv[q] = wp[q];
            const float* wf = (const float*)wv;
#pragma unroll
            for (int ch = 0; ch < 27; ++ch) {
                acc[0][ch] = fmaf(wf[ch], xv0[tap], acc[0][ch]);
                acc[1][ch] = fmaf(wf[ch], xv1[tap], acc[1][ch]);
            }
        }
    }

    const int  r0 = p0 & 16383, r1 = p1 & 16383;
    const long ob = ((long)b * 27) << 14;
#pragma unroll
    for (int ch = 0; ch < 27; ++ch) {
        off[ob + ((long)ch << 14) + r0] = acc[0][ch];
        off[ob + ((long)ch << 14) + r1] = acc[1][ch];
    }
}

// ---------------------------------------------------------------------------
// Kernel B: main deformable conv.
// One block per (b, h) row: 128 positions x 64 output channels.
// Phase 1: per (k,pos) bilinear params into LDS (mask & validity folded in).
// Phase 2: per k: stage w_dcn k-slice; gather val[c][pos] in two 32-c halves;
//          each thread accumulates a 4-pos x 8-cout register tile.
// ---------------------------------------------------------------------------
__launch_bounds__(256)
__global__ void dcn_main(const float* __restrict__ x, const float* __restrict__ off,
                         const float* __restrict__ wt, float* __restrict__ out) {
    __shared__ unsigned int pk[KKn * Wn];            //  4608 B packed corner indices
    __shared__ float ay0[KKn * Wn], ay1[KKn * Wn];   // 18432 B weights (mask folded)
    __shared__ float ax0[KKn * Wn], ax1[KKn * Wn];
    __shared__ float wk[CINn * COUTn];               // 16384 B  [c][o]
    __shared__ float val[32 * Wn];                   // 16384 B  [cl][pos]

    const int blk = blockIdx.x;
    const int b = blk >> 7, h = blk & 127;
    const int t = threadIdx.x;

    // ---- phase 1: bilinear params ----
    for (int e = t; e < KKn * Wn; e += 256) {
        int k = e >> 7, pos = e & 127;
        const float* offb = off + (((long)b * 27) << 14) + (h << 7) + pos;
        float dy = offb[(long)(2 * k) << 14];
        float dx = offb[(long)(2 * k + 1) << 14];
        float m  = offb[(long)(18 + k) << 14];
        m = 1.f / (1.f + expf(-m));
        float py = (float)(h + (k / 3) - 1) + dy;
        float px = (float)(pos + (k % 3) - 1) + dx;
        float fy = floorf(py), fx = floorf(px);
        int y0 = (int)fy, x0 = (int)fx;
        int y1 = y0 + 1, x1 = x0 + 1;
        float wy1 = py - fy, wx1 = px - fx;
        float a_y0 = (y0 >= 0 && y0 < Hn) ? (1.f - wy1) * m : 0.f;
        float a_y1 = (y1 >= 0 && y1 < Hn) ? wy1 * m : 0.f;
        float a_x0 = (x0 >= 0 && x0 < Wn) ? (1.f - wx1) : 0.f;
        float a_x1 = (x1 >= 0 && x1 < Wn) ? wx1 : 0.f;
        int y0c = min(max(y0, 0), Hn - 1), y1c = min(max(y1, 0), Hn - 1);
        int x0c = min(max(x0, 0), Wn - 1), x1c = min(max(x1, 0), Wn - 1);
        pk[e] = (unsigned)y0c | ((unsigned)y1c << 8) | ((unsigned)x0c << 16) | ((unsigned)x1c << 24);
        ay0[e] = a_y0; ay1[e] = a_y1; ax0[e] = a_x0; ax1[e] = a_x1;
    }

    float accv[4][8];
#pragma unroll
    for (int j = 0; j < 4; ++j)
#pragma unroll
        for (int i = 0; i < 8; ++i) accv[j][i] = 0.f;

    const int p  = t & 31;
    const int o0 = (t >> 5) * 8;
    const float* xb = x + (((long)b * CINn) << 14);

    for (int k = 0; k < KKn; ++k) {
        __syncthreads();   // previous compute done before overwriting wk / val
        for (int e = t; e < 4096; e += 256) wk[e] = wt[k * 4096 + e];

#pragma unroll
        for (int half = 0; half < 2; ++half) {
            if (half == 1) __syncthreads();   // compute(half0) done before val overwrite
            // ---- gather ----
#pragma unroll
            for (int i = 0; i < 16; ++i) {
                int e = t + 256 * i;          // 0..4095
                int pos = e & 127, cl = e >> 7;
                int c = half * 32 + cl;
                unsigned pkv = pk[(k << 7) + pos];
                int y0c = pkv & 255, y1c = (pkv >> 8) & 255;
                int x0c = (pkv >> 16) & 255, x1c = pkv >> 24;
                float a0 = ay0[(k << 7) + pos], a1 = ay1[(k << 7) + pos];
                float b0 = ax0[(k << 7) + pos], b1 = ax1[(k << 7) + pos];
                const float* xc = xb + ((long)c << 14);
                float v00 = xc[(y0c << 7) + x0c];
                float v01 = xc[(y0c << 7) + x1c];
                float v10 = xc[(y1c << 7) + x0c];
                float v11 = xc[(y1c << 7) + x1c];
                val[cl * 128 + pos] = a0 * (b0 * v00 + b1 * v01) + a1 * (b0 * v10 + b1 * v11);
            }
            __syncthreads();                  // val + wk ready
            // ---- compute ----
            for (int cl = 0; cl < 32; ++cl) {
                const float4 wv0 = *(const float4*)&wk[(half * 32 + cl) * 64 + o0];
                const float4 wv1 = *(const float4*)&wk[(half * 32 + cl) * 64 + o0 + 4];
                float wreg[8] = {wv0.x, wv0.y, wv0.z, wv0.w, wv1.x, wv1.y, wv1.z, wv1.w};
                float vreg[4];
                vreg[0] = val[cl * 128 + p];
                vreg[1] = val[cl * 128 + p + 32];
                vreg[2] = val[cl * 128 + p + 64];
                vreg[3] = val[cl * 128 + p + 96];
#pragma unroll
                for (int j = 0; j < 4; ++j)
#pragma unroll
                    for (int i = 0; i < 8; ++i)
                        accv[j][i] = fmaf(vreg[j], wreg[i], accv[j][i]);
            }
        }
    }

    const long outb = (((long)b * COUTn) << 14) + (h << 7);
#pragma unroll
    for (int i = 0; i < 8; ++i)
#pragma unroll
        for (int j = 0; j < 4; ++j)
            out[outb + ((long)(o0 + i) << 14) + p + 32 * j] = accv[j][i];
}

// ---------------------------------------------------------------------------
extern "C" void kernel_launch(void* const* d_in, const int* in_sizes, int n_in,
                              void* d_out, int out_size, void* d_ws, size_t ws_size,
                              hipStream_t stream) {
    const float* x     = (const float*)d_in[0];
    const float* w_off = (const float*)d_in[1];
    const float* b_off = (const float*)d_in[2];
    const float* w_dcn = (const float*)d_in[3];
    float* out = (float*)d_out;

    float* wt  = (float*)d_ws;                  // 36864 floats
    float* off = wt + 36864;                    // 8*27*16384 = 3538944 floats

    wdcn_transpose<<<144, 256, 0, stream>>>(w_dcn, wt);
    offconv<<<256, 256, 0, stream>>>(x, w_off, b_off, off);
    dcn_main<<<Bn * Hn, 256, 0, stream>>>(x, off, wt, out);
}

// Round 3
// 374.761 us; speedup vs baseline: 1.5862x; 1.5862x over previous
//
#include <hip/hip_runtime.h>

#define Bn 8
#define CINn 64
#define COUTn 64
#define Hn 128
#define Wn 128
#define KKn 9

typedef __attribute__((ext_vector_type(8))) short short8v;   // 8 bf16 (4 VGPR)
typedef __attribute__((ext_vector_type(4))) float f32x4;     // MFMA accumulator

__device__ __forceinline__ unsigned short f2bf(float f) {
    unsigned u = __float_as_uint(f);
    unsigned r = (u + 0x7FFFu + ((u >> 16) & 1u)) >> 16;     // RNE
    return (unsigned short)r;
}

// ---------------------------------------------------------------------------
// Kernel A2: w_dcn (COUT, CIN, 3,3) -> bf16 w2[k][o][c]
// ---------------------------------------------------------------------------
__global__ void wdcn_prep(const float* __restrict__ w_dcn, unsigned short* __restrict__ w2) {
    int i = blockIdx.x * 256 + threadIdx.x;          // 36864 total = [k][o][c]
    if (i >= COUTn * CINn * KKn) return;
    int c = i & 63;
    int o = (i >> 6) & 63;
    int k = i >> 12;
    w2[i] = f2bf(w_dcn[(o * CINn + c) * KKn + k]);
}

// ---------------------------------------------------------------------------
// Kernel A: offset conv (unchanged, fp32).
// ---------------------------------------------------------------------------
__launch_bounds__(256)
__global__ void offconv(const float* __restrict__ x, const float* __restrict__ w_off,
                        const float* __restrict__ b_off, float* __restrict__ off) {
    __shared__ float lw[CINn * KKn * 28];            // 64512 B
    for (int e = threadIdx.x; e < 27 * CINn * KKn; e += 256) {
        int tap = e % 9;
        int c   = (e / 9) & 63;
        int ch  = e / 576;
        lw[(c * 9 + tap) * 28 + ch] = w_off[e];
    }
    __syncthreads();

    const int t    = threadIdx.x;
    const int base = blockIdx.x * 512;
    const int p0   = base + t;
    const int p1   = base + 256 + t;
    const int b    = p0 >> 14;
    const int h0 = (p0 >> 7) & 127, w0 = p0 & 127;
    const int h1 = (p1 >> 7) & 127, w1 = p1 & 127;

    float acc[2][27];
#pragma unroll
    for (int ch = 0; ch < 27; ++ch) {
        float bv = b_off[ch];
        acc[0][ch] = bv;
        acc[1][ch] = bv;
    }

    for (int c = 0; c < CINn; ++c) {
        const float* xc = x + (((long)b * CINn + c) << 14);
        float xv0[9], xv1[9];
#pragma unroll
        for (int di = 0; di < 3; ++di) {
#pragma unroll
            for (int dj = 0; dj < 3; ++dj) {
                int y = h0 + di - 1, xx = w0 + dj - 1;
                xv0[di * 3 + dj] = (y >= 0 && y < Hn && xx >= 0 && xx < Wn) ? xc[(y << 7) + xx] : 0.f;
                y = h1 + di - 1; xx = w1 + dj - 1;
                xv1[di * 3 + dj] = (y >= 0 && y < Hn && xx >= 0 && xx < Wn) ? xc[(y << 7) + xx] : 0.f;
            }
        }
#pragma unroll
        for (int tap = 0; tap < 9; ++tap) {
            const float4* wp = (const float4*)&lw[(c * 9 + tap) * 28];
            float4 wv[7];
#pragma unroll
            for (int q = 0; q < 7; ++q) wv[q] = wp[q];
            const float* wf = (const float*)wv;
#pragma unroll
            for (int ch = 0; ch < 27; ++ch) {
                acc[0][ch] = fmaf(wf[ch], xv0[tap], acc[0][ch]);
                acc[1][ch] = fmaf(wf[ch], xv1[tap], acc[1][ch]);
            }
        }
    }

    const int  r0 = p0 & 16383, r1 = p1 & 16383;
    const long ob = ((long)b * 27) << 14;
#pragma unroll
    for (int ch = 0; ch < 27; ++ch) {
        off[ob + ((long)ch << 14) + r0] = acc[0][ch];
        off[ob + ((long)ch << 14) + r1] = acc[1][ch];
    }
}

// ---------------------------------------------------------------------------
// Kernel B: deformable conv main, MFMA version.
// Block = (b, h): 256 thr / 4 waves.  Per k: stage bf16 w[o][c] (XOR-swz),
// gather val bf16 [pos][c] (XOR-swz), 16x16x32 bf16 MFMA, fp32 accum.
// Wave quadrant: 32 cout x 64 pos.  LDS 46.5 KB -> 3 blocks/CU.
// ---------------------------------------------------------------------------
__launch_bounds__(256)
__global__ void dcn_main(const float* __restrict__ x, const float* __restrict__ off,
                         const unsigned short* __restrict__ w2, float* __restrict__ out) {
    __shared__ unsigned int pk[KKn * Wn];                 //  4608 B
    __shared__ float ay0[KKn * Wn], ay1[KKn * Wn];        // 18432 B
    __shared__ float ax0[KKn * Wn], ax1[KKn * Wn];
    __shared__ alignas(16) unsigned short wlds[4096];     //  8192 B  [o][c] bf16, swz
    __shared__ alignas(16) unsigned short vlds[8192];     // 16384 B  [pos][c] bf16, swz

    const int blk = blockIdx.x;
    const int b = blk >> 7, h = blk & 127;
    const int t = threadIdx.x;

    // ---- phase 1: bilinear params (mask & validity folded into weights) ----
    for (int e = t; e < KKn * Wn; e += 256) {
        int k = e >> 7, pos = e & 127;
        const float* offb = off + (((long)b * 27) << 14) + (h << 7) + pos;
        float dy = offb[(long)(2 * k) << 14];
        float dx = offb[(long)(2 * k + 1) << 14];
        float m  = offb[(long)(18 + k) << 14];
        m = 1.f / (1.f + expf(-m));
        float py = (float)(h + (k / 3) - 1) + dy;
        float px = (float)(pos + (k % 3) - 1) + dx;
        float fy = floorf(py), fx = floorf(px);
        int y0 = (int)fy, x0 = (int)fx;
        int y1 = y0 + 1, x1 = x0 + 1;
        float wy1 = py - fy, wx1 = px - fx;
        float a_y0 = (y0 >= 0 && y0 < Hn) ? (1.f - wy1) * m : 0.f;
        float a_y1 = (y1 >= 0 && y1 < Hn) ? wy1 * m : 0.f;
        float a_x0 = (x0 >= 0 && x0 < Wn) ? (1.f - wx1) : 0.f;
        float a_x1 = (x1 >= 0 && x1 < Wn) ? wx1 : 0.f;
        int y0c = min(max(y0, 0), Hn - 1), y1c = min(max(y1, 0), Hn - 1);
        int x0c = min(max(x0, 0), Wn - 1), x1c = min(max(x1, 0), Wn - 1);
        pk[e] = (unsigned)y0c | ((unsigned)y1c << 8) | ((unsigned)x0c << 16) | ((unsigned)x1c << 24);
        ay0[e] = a_y0; ay1[e] = a_y1; ax0[e] = a_x0; ax1[e] = a_x1;
    }

    f32x4 acc[2][4];
#pragma unroll
    for (int ot = 0; ot < 2; ++ot)
#pragma unroll
        for (int pt = 0; pt < 4; ++pt)
            acc[ot][pt] = (f32x4){0.f, 0.f, 0.f, 0.f};

    const int lane  = t & 63;
    const int wv    = t >> 6;
    const int ohalf = wv & 1;          // cout half (0/1 -> o base 0/32)
    const int phalf = wv >> 1;         // pos half  (0/1 -> pos base 0/64)
    const int sub   = lane >> 4;       // k-subchunk within frag
    const int r16   = lane & 15;
    const int gpos  = t & 127;         // gather: fixed pos per thread
    const int cp0   = t >> 7;          // gather: c-pair parity
    const float* xb = x + (((long)b * CINn) << 14);

    for (int k = 0; k < KKn; ++k) {
        __syncthreads();   // prior MFMA reads done before overwriting wlds/vlds

        // ---- stage w_k: global [k][o][c] bf16 -> LDS [o][chunk^ (o&7)] ----
#pragma unroll
        for (int i = 0; i < 2; ++i) {
            int q  = t + 256 * i;              // 16B chunk id, 0..511
            int o  = q >> 3, ch = q & 7;
            short8v w8 = *(const short8v*)(w2 + (k << 12) + (q << 3));
            *(short8v*)&wlds[(o << 6) + (((ch ^ (o & 7))) << 3)] = w8;
        }

        // ---- gather: 2 channels per iter, pack 2 bf16, swizzled b32 write ----
        {
            unsigned pkv = pk[(k << 7) + gpos];
            float a0 = ay0[(k << 7) + gpos], a1 = ay1[(k << 7) + gpos];
            float b0 = ax0[(k << 7) + gpos], b1 = ax1[(k << 7) + gpos];
            int y0c = pkv & 255, y1c = (pkv >> 8) & 255;
            int x0c = (pkv >> 16) & 255, x1c = pkv >> 24;
            int i00 = (y0c << 7) + x0c, i01 = (y0c << 7) + x1c;
            int i10 = (y1c << 7) + x0c, i11 = (y1c << 7) + x1c;
#pragma unroll 4
            for (int it = 0; it < 16; ++it) {
                int cpair = cp0 + 2 * it;
                const float* xc0 = xb + ((long)(2 * cpair) << 14);
                const float* xc1 = xc0 + 16384;
                float v000 = xc0[i00], v001 = xc0[i01], v010 = xc0[i10], v011 = xc0[i11];
                float v100 = xc1[i00], v101 = xc1[i01], v110 = xc1[i10], v111 = xc1[i11];
                float val0 = a0 * (b0 * v000 + b1 * v001) + a1 * (b0 * v010 + b1 * v011);
                float val1 = a0 * (b0 * v100 + b1 * v101) + a1 * (b0 * v110 + b1 * v111);
                unsigned pkd = (unsigned)f2bf(val0) | ((unsigned)f2bf(val1) << 16);
                int cs = (cpair >> 2) ^ (gpos & 7);
                *(unsigned*)&vlds[(gpos << 6) + (cs << 3) + ((cpair & 3) << 1)] = pkd;
            }
        }
        __syncthreads();   // wlds + vlds ready

        // ---- MFMA: acc[ot][pt] += w x val over this k's 64 channels ----
#pragma unroll
        for (int kk = 0; kk < 2; ++kk) {
            const int cc = kk * 4 + sub;       // c chunk index 0..7
            short8v af[2], bf[4];
#pragma unroll
            for (int ot = 0; ot < 2; ++ot) {
                int o = ohalf * 32 + ot * 16 + r16;
                af[ot] = *(const short8v*)&wlds[(o << 6) + ((cc ^ (o & 7)) << 3)];
            }
#pragma unroll
            for (int pt = 0; pt < 4; ++pt) {
                int pos = phalf * 64 + pt * 16 + r16;
                bf[pt] = *(const short8v*)&vlds[(pos << 6) + ((cc ^ (pos & 7)) << 3)];
            }
#pragma unroll
            for (int ot = 0; ot < 2; ++ot)
#pragma unroll
                for (int pt = 0; pt < 4; ++pt)
                    acc[ot][pt] = __builtin_amdgcn_mfma_f32_16x16x32_bf16(af[ot], bf[pt], acc[ot][pt], 0, 0, 0);
        }
    }

    // ---- epilogue: D col=lane&15 (pos), row=(lane>>4)*4+reg (cout) ----
    const long base = (((long)b * COUTn) << 14) + (h << 7);
#pragma unroll
    for (int ot = 0; ot < 2; ++ot)
#pragma unroll
        for (int pt = 0; pt < 4; ++pt) {
#pragma unroll
            for (int r = 0; r < 4; ++r) {
                int o   = ohalf * 32 + ot * 16 + sub * 4 + r;
                int pos = phalf * 64 + pt * 16 + r16;
                out[base + ((long)o << 14) + pos] = acc[ot][pt][r];
            }
        }
}

// ---------------------------------------------------------------------------
extern "C" void kernel_launch(void* const* d_in, const int* in_sizes, int n_in,
                              void* d_out, int out_size, void* d_ws, size_t ws_size,
                              hipStream_t stream) {
    const float* x     = (const float*)d_in[0];
    const float* w_off = (const float*)d_in[1];
    const float* b_off = (const float*)d_in[2];
    const float* w_dcn = (const float*)d_in[3];
    float* out = (float*)d_out;

    unsigned short* w2 = (unsigned short*)d_ws;              // 36864 ushort = 73728 B
    float* off = (float*)((char*)d_ws + 73728);              // 8*27*16384 floats

    wdcn_prep<<<144, 256, 0, stream>>>(w_dcn, w2);
    offconv<<<256, 256, 0, stream>>>(x, w_off, b_off, off);
    dcn_main<<<Bn * Hn, 256, 0, stream>>>(x, off, w2, out);
}

// Round 5
// 297.903 us; speedup vs baseline: 1.9955x; 1.2580x over previous
//
#include <hip/hip_runtime.h>

#define Bn 8
#define CINn 64
#define COUTn 64
#define Hn 128
#define Wn 128
#define KKn 9

typedef __attribute__((ext_vector_type(8))) short short8v;   // 8 bf16 (4 VGPR)
typedef __attribute__((ext_vector_type(4))) float f32x4;     // MFMA accumulator

__device__ __forceinline__ unsigned short f2bf(float f) {
    unsigned u = __float_as_uint(f);
    unsigned r = (u + 0x7FFFu + ((u >> 16) & 1u)) >> 16;     // RNE
    return (unsigned short)r;
}

// ---------------------------------------------------------------------------
// wdcn_prep: w_dcn (COUT, CIN, 3,3) -> bf16 w2[k][o][c]
// ---------------------------------------------------------------------------
__global__ void wdcn_prep(const float* __restrict__ w_dcn, unsigned short* __restrict__ w2) {
    int i = blockIdx.x * 256 + threadIdx.x;          // 36864 = [k][o][c]
    if (i >= COUTn * CINn * KKn) return;
    int c = i & 63;
    int o = (i >> 6) & 63;
    int k = i >> 12;
    w2[i] = f2bf(w_dcn[(o * CINn + c) * KKn + k]);
}

// ---------------------------------------------------------------------------
// woffprep: w_off (27, 64, 3,3) -> bf16 wofft[tap][ch pad32][c]  (zeros ch>=27)
// ---------------------------------------------------------------------------
__global__ void woffprep(const float* __restrict__ w_off, unsigned short* __restrict__ wofft) {
    int i = blockIdx.x * 256 + threadIdx.x;          // 18432 = [tap][ch][c]
    if (i >= 9 * 32 * 64) return;
    int c   = i & 63;
    int ch  = (i >> 6) & 31;
    int tap = i >> 11;
    wofft[i] = (ch < 27) ? f2bf(w_off[(ch * 64 + c) * 9 + tap]) : (unsigned short)0;
}

// ---------------------------------------------------------------------------
// offconv_mfma: off[b][27][h][w] via MFMA.  Block = (b, h-pair): M=32(27),
// N=256 (2 rows x 128 w), K=576.  Per di: stage 2 rows XT[2][130][64] bf16
// (XOR-swz, zero pad cols), A-frags from global wofft (L2-hot).
// ---------------------------------------------------------------------------
__launch_bounds__(256)
__global__ void offconv_mfma(const float* __restrict__ x,
                             const unsigned short* __restrict__ wofft,
                             const float* __restrict__ b_off, float* __restrict__ off) {
    __shared__ alignas(16) unsigned short XT[2 * 130 * 64];   // 33280 B

    int blk = blockIdx.x;
    blk = (blk & 7) * 64 + (blk >> 3);               // XCD swizzle: b = origBlk & 7
    const int b  = blk >> 6, hp = blk & 63;
    const int r0 = hp * 2;
    const int t  = threadIdx.x;
    const int lane = t & 63, wv = t >> 6;
    const int r16 = lane & 15, sub = lane >> 4;
    const int sw = t & 127, chalf = t >> 7;

    f32x4 acc[2][4];
#pragma unroll
    for (int mt = 0; mt < 2; ++mt)
#pragma unroll
        for (int nt = 0; nt < 4; ++nt) acc[mt][nt] = (f32x4){0.f, 0.f, 0.f, 0.f};

    // zero pad columns (wslot 0 and 129) once; never overwritten
    if (t < 128) {
        int rs = t >> 6, which = (t >> 5) & 1, cpair = t & 31;
        int wslot = which ? 129 : 0;
        int c0 = cpair * 2;
        *(unsigned*)&XT[((rs * 130 + wslot) << 6) + (((c0 >> 3) ^ (wslot & 7)) << 3) + (c0 & 7)] = 0;
    }

    const float* xbase = x + (((long)b * CINn) << 14);

    for (int di = 0; di < 3; ++di) {
        if (di) __syncthreads();                     // WAR on XT
        // ---- stage rows r0+rs+di-1 as XT[rs][w+1][c] (f32 -> bf16 pairs) ----
#pragma unroll
        for (int rs = 0; rs < 2; ++rs) {
            int y = r0 + rs + di - 1;
            bool inb = (y >= 0 && y < Hn);
            int yc = inb ? y : 0;
            const float* xr = xbase + (yc << 7) + sw;
            int wslot = sw + 1;
#pragma unroll 4
            for (int cp = 0; cp < 16; ++cp) {
                int c0 = (chalf * 16 + cp) * 2;
                unsigned v = 0;
                if (inb) {
                    float lo = xr[(long)c0 << 14];
                    float hi = xr[(long)(c0 + 1) << 14];
                    v = (unsigned)f2bf(lo) | ((unsigned)f2bf(hi) << 16);
                }
                *(unsigned*)&XT[((rs * 130 + wslot) << 6) + (((c0 >> 3) ^ (wslot & 7)) << 3) + (c0 & 7)] = v;
            }
        }
        __syncthreads();                             // XT ready

        // ---- MFMA: 3 dj x 2 kk; A from global wofft; B from XT ----
#pragma unroll
        for (int dj = 0; dj < 3; ++dj) {
            int tap = di * 3 + dj;
#pragma unroll
            for (int kk = 0; kk < 2; ++kk) {
                short8v a0 = *(const short8v*)(wofft + ((tap * 32 +      r16) << 6) + ((kk * 4 + sub) << 3));
                short8v a1 = *(const short8v*)(wofft + ((tap * 32 + 16 + r16) << 6) + ((kk * 4 + sub) << 3));
                short8v bfr[4];
#pragma unroll
                for (int nt = 0; nt < 4; ++nt) {
                    int ntile = wv * 4 + nt;
                    int hsel = ntile >> 3, wbase = (ntile & 7) * 16;
                    int wslot = wbase + r16 + dj;    // 0..129
                    int cchunk = kk * 4 + sub;
                    bfr[nt] = *(const short8v*)&XT[((hsel * 130 + wslot) << 6) + ((cchunk ^ (wslot & 7)) << 3)];
                }
#pragma unroll
                for (int nt = 0; nt < 4; ++nt) {
                    acc[0][nt] = __builtin_amdgcn_mfma_f32_16x16x32_bf16(a0, bfr[nt], acc[0][nt], 0, 0, 0);
                    acc[1][nt] = __builtin_amdgcn_mfma_f32_16x16x32_bf16(a1, bfr[nt], acc[1][nt], 0, 0, 0);
                }
            }
        }
    }

    // ---- epilogue: D col=lane&15 (w), row=sub*4+r (ch); bias add ----
#pragma unroll
    for (int mt = 0; mt < 2; ++mt)
#pragma unroll
        for (int nt = 0; nt < 4; ++nt) {
            int ntile = wv * 4 + nt;
            int hsel = ntile >> 3, w = (ntile & 7) * 16 + r16;
            int h = r0 + hsel;
#pragma unroll
            for (int r = 0; r < 4; ++r) {
                int ch = mt * 16 + sub * 4 + r;
                if (ch < 27)
                    off[(((long)(b * 27 + ch)) << 14) + (h << 7) + w] = acc[mt][nt][r] + b_off[ch];
            }
        }
}

// ---------------------------------------------------------------------------
// dcn_main: MFMA deformable conv.  Params computed inline per k (no LDS
// tables -> LDS 24.6 KB).  f32 x gather, per-XCD batch residency via swizzle.
// ---------------------------------------------------------------------------
__launch_bounds__(256)
__global__ void dcn_main(const float* __restrict__ x, const float* __restrict__ off,
                         const unsigned short* __restrict__ w2, float* __restrict__ out) {
    __shared__ alignas(16) unsigned short wlds[4096];     //  8192 B  [o][c] bf16, swz
    __shared__ alignas(16) unsigned short vlds[8192];     // 16384 B  [pos][c] bf16, swz

    int blk = blockIdx.x;
    blk = (blk & 7) * 128 + (blk >> 3);              // XCD swizzle: b = origBlk & 7
    const int b = blk >> 7, h = blk & 127;
    const int t = threadIdx.x;

    f32x4 acc[2][4];
#pragma unroll
    for (int ot = 0; ot < 2; ++ot)
#pragma unroll
        for (int pt = 0; pt < 4; ++pt)
            acc[ot][pt] = (f32x4){0.f, 0.f, 0.f, 0.f};

    const int lane  = t & 63;
    const int wv    = t >> 6;
    const int ohalf = wv & 1;
    const int phalf = wv >> 1;
    const int sub   = lane >> 4;
    const int r16   = lane & 15;
    const int gpos  = t & 127;
    const int cp0   = t >> 7;
    const float* xb = x + (((long)b * CINn) << 14);
    const float* offb = off + (((long)b * 27) << 14) + (h << 7) + gpos;

    for (int k = 0; k < KKn; ++k) {
        __syncthreads();   // prior MFMA reads done before overwriting wlds/vlds

        // ---- stage w_k: [k][o][c] bf16 -> LDS [o][chunk ^ (o&7)] ----
#pragma unroll
        for (int i = 0; i < 2; ++i) {
            int q  = t + 256 * i;
            int o  = q >> 3, ch = q & 7;
            short8v w8 = *(const short8v*)(w2 + (k << 12) + (q << 3));
            *(short8v*)&wlds[(o << 6) + ((ch ^ (o & 7)) << 3)] = w8;
        }

        // ---- bilinear params inline (mask & validity folded into weights) ----
        float dy = offb[(long)(2 * k) << 14];
        float dx = offb[(long)(2 * k + 1) << 14];
        float m  = offb[(long)(18 + k) << 14];
        m = 1.f / (1.f + __expf(-m));
        float py = (float)(h + (k / 3) - 1) + dy;
        float px = (float)(gpos + (k % 3) - 1) + dx;
        float fy = floorf(py), fx = floorf(px);
        int y0 = (int)fy, x0 = (int)fx;
        int y1 = y0 + 1, x1 = x0 + 1;
        float wy1 = py - fy, wx1 = px - fx;
        float a0 = (y0 >= 0 && y0 < Hn) ? (1.f - wy1) * m : 0.f;
        float a1 = (y1 >= 0 && y1 < Hn) ? wy1 * m : 0.f;
        float b0 = (x0 >= 0 && x0 < Wn) ? (1.f - wx1) : 0.f;
        float b1 = (x1 >= 0 && x1 < Wn) ? wx1 : 0.f;
        int y0c = min(max(y0, 0), Hn - 1), y1c = min(max(y1, 0), Hn - 1);
        int x0c = min(max(x0, 0), Wn - 1), x1c = min(max(x1, 0), Wn - 1);
        int i00 = (y0c << 7) + x0c, i01 = (y0c << 7) + x1c;
        int i10 = (y1c << 7) + x0c, i11 = (y1c << 7) + x1c;

        // ---- gather: 2 channels per iter, pack 2 bf16, swizzled b32 write ----
#pragma unroll 4
        for (int it = 0; it < 16; ++it) {
            int cpair = cp0 + 2 * it;
            const float* xc0 = xb + ((long)(2 * cpair) << 14);
            const float* xc1 = xc0 + 16384;
            float v000 = xc0[i00], v001 = xc0[i01], v010 = xc0[i10], v011 = xc0[i11];
            float v100 = xc1[i00], v101 = xc1[i01], v110 = xc1[i10], v111 = xc1[i11];
            float val0 = a0 * (b0 * v000 + b1 * v001) + a1 * (b0 * v010 + b1 * v011);
            float val1 = a0 * (b0 * v100 + b1 * v101) + a1 * (b0 * v110 + b1 * v111);
            unsigned pkd = (unsigned)f2bf(val0) | ((unsigned)f2bf(val1) << 16);
            int cs = (cpair >> 2) ^ (gpos & 7);
            *(unsigned*)&vlds[(gpos << 6) + (cs << 3) + ((cpair & 3) << 1)] = pkd;
        }
        __syncthreads();   // wlds + vlds ready

        // ---- MFMA ----
#pragma unroll
        for (int kk = 0; kk < 2; ++kk) {
            const int cc = kk * 4 + sub;
            short8v af[2], bf[4];
#pragma unroll
            for (int ot = 0; ot < 2; ++ot) {
                int o = ohalf * 32 + ot * 16 + r16;
                af[ot] = *(const short8v*)&wlds[(o << 6) + ((cc ^ (o & 7)) << 3)];
            }
#pragma unroll
            for (int pt = 0; pt < 4; ++pt) {
                int pos = phalf * 64 + pt * 16 + r16;
                bf[pt] = *(const short8v*)&vlds[(pos << 6) + ((cc ^ (pos & 7)) << 3)];
            }
#pragma unroll
            for (int ot = 0; ot < 2; ++ot)
#pragma unroll
                for (int pt = 0; pt < 4; ++pt)
                    acc[ot][pt] = __builtin_amdgcn_mfma_f32_16x16x32_bf16(af[ot], bf[pt], acc[ot][pt], 0, 0, 0);
        }
    }

    // ---- epilogue ----
    const long obase = (((long)b * COUTn) << 14) + (h << 7);
#pragma unroll
    for (int ot = 0; ot < 2; ++ot)
#pragma unroll
        for (int pt = 0; pt < 4; ++pt) {
#pragma unroll
            for (int r = 0; r < 4; ++r) {
                int o   = ohalf * 32 + ot * 16 + sub * 4 + r;
                int pos = phalf * 64 + pt * 16 + r16;
                out[obase + ((long)o << 14) + pos] = acc[ot][pt][r];
            }
        }
}

// ---------------------------------------------------------------------------
extern "C" void kernel_launch(void* const* d_in, const int* in_sizes, int n_in,
                              void* d_out, int out_size, void* d_ws, size_t ws_size,
                              hipStream_t stream) {
    const float* x     = (const float*)d_in[0];
    const float* w_off = (const float*)d_in[1];
    const float* b_off = (const float*)d_in[2];
    const float* w_dcn = (const float*)d_in[3];
    float* out = (float*)d_out;

    unsigned short* w2    = (unsigned short*)d_ws;                   //  73728 B
    unsigned short* wofft = (unsigned short*)((char*)d_ws + 73728);  //  36864 B
    float*          off   = (float*)((char*)d_ws + 110592);          // 14155776 B

    wdcn_prep<<<144, 256, 0, stream>>>(w_dcn, w2);
    woffprep<<<72, 256, 0, stream>>>(w_off, wofft);
    offconv_mfma<<<512, 256, 0, stream>>>(x, wofft, b_off, off);
    dcn_main<<<Bn * Hn, 256, 0, stream>>>(x, off, w2, out);
}

// Round 6
// 257.309 us; speedup vs baseline: 2.3103x; 1.1578x over previous
//
#include <hip/hip_runtime.h>

#define Bn 8
#define CINn 64
#define COUTn 64
#define Hn 128
#define Wn 128
#define KKn 9

typedef __attribute__((ext_vector_type(8))) short short8v;   // 8 bf16 (4 VGPR)
typedef __attribute__((ext_vector_type(4))) float f32x4;     // MFMA accumulator

__device__ __forceinline__ unsigned short f2bf(float f) {
    unsigned u = __float_as_uint(f);
    unsigned r = (u + 0x7FFFu + ((u >> 16) & 1u)) >> 16;     // RNE
    return (unsigned short)r;
}
__device__ __forceinline__ float bf2f(unsigned short u) {
    return __uint_as_float(((unsigned)u) << 16);
}

// ---------------------------------------------------------------------------
// xt_prep: x f32 NCHW -> xt bf16 NHWC  (xt[b][y][x][c], c contiguous)
// Block = (b,y).  LDS tile [x][c] padded to 68 (4-way max on u16 writes,
// b64-aligned reads), then contiguous 16B global stores.
// ---------------------------------------------------------------------------
__launch_bounds__(256)
__global__ void xt_prep(const float* __restrict__ x, unsigned short* __restrict__ xt) {
    __shared__ unsigned short tile[128 * 68];        // 17408 B
    const int blk = blockIdx.x;
    const int b = blk >> 7, y = blk & 127;
    const int t = threadIdx.x;
    const float* xb = x + (((long)b * CINn) << 14) + (y << 7);
#pragma unroll
    for (int i = 0; i < 32; ++i) {
        int e = i * 256 + t;                         // c = e>>7, xx = e&127
        int c = e >> 7, xx = e & 127;
        tile[xx * 68 + c] = f2bf(xb[((long)c << 14) + xx]);
    }
    __syncthreads();
    unsigned short* dst = xt + ((long)(b * 128 + y) << 13);
#pragma unroll
    for (int i = 0; i < 4; ++i) {
        int q = i * 256 + t;                         // 16B chunk: xx = q>>3, j = q&7
        int xx = q >> 3, j = q & 7;
        const unsigned long long* src = (const unsigned long long*)&tile[xx * 68 + j * 8];
        unsigned long long v0 = src[0], v1 = src[1];
        unsigned long long* d = (unsigned long long*)&dst[q * 8];
        d[0] = v0; d[1] = v1;
    }
}

// ---------------------------------------------------------------------------
// wdcn_prep: w_dcn (COUT, CIN, 3,3) -> bf16 w2[k][o][c]
// ---------------------------------------------------------------------------
__global__ void wdcn_prep(const float* __restrict__ w_dcn, unsigned short* __restrict__ w2) {
    int i = blockIdx.x * 256 + threadIdx.x;          // 36864 = [k][o][c]
    if (i >= COUTn * CINn * KKn) return;
    int c = i & 63;
    int o = (i >> 6) & 63;
    int k = i >> 12;
    w2[i] = f2bf(w_dcn[(o * CINn + c) * KKn + k]);
}

// ---------------------------------------------------------------------------
// woffprep: w_off (27, 64, 3,3) -> bf16 wofft[tap][ch pad32][c]  (zeros ch>=27)
// ---------------------------------------------------------------------------
__global__ void woffprep(const float* __restrict__ w_off, unsigned short* __restrict__ wofft) {
    int i = blockIdx.x * 256 + threadIdx.x;          // 18432 = [tap][ch][c]
    if (i >= 9 * 32 * 64) return;
    int c   = i & 63;
    int ch  = (i >> 6) & 31;
    int tap = i >> 11;
    wofft[i] = (ch < 27) ? f2bf(w_off[(ch * 64 + c) * 9 + tap]) : (unsigned short)0;
}

// ---------------------------------------------------------------------------
// offconv_direct: off via MFMA, zero LDS.  Block = (b, h-pair); M=32(27ch),
// N=256 (2 rows x 128 w), K=576.  B-frags loaded straight from xt (NHWC);
// out-of-bounds taps -> zero frag.  A-frags from global wofft (L2-hot).
// Output off stored bf16 planar [b][27][h][w].
// ---------------------------------------------------------------------------
__launch_bounds__(256)
__global__ void offconv_direct(const unsigned short* __restrict__ xt,
                               const unsigned short* __restrict__ wofft,
                               const float* __restrict__ b_off,
                               unsigned short* __restrict__ offo) {
    int blk = blockIdx.x;
    blk = (blk & 7) * 64 + (blk >> 3);               // XCD swizzle: b = origBlk & 7
    const int b  = blk >> 6, hp = blk & 63;
    const int r0 = hp * 2;
    const int t  = threadIdx.x;
    const int lane = t & 63, wv = t >> 6;
    const int r16 = lane & 15, sub = lane >> 4;
    const unsigned short* xtb = xt + ((long)b << 20);

    f32x4 acc[2][4];
#pragma unroll
    for (int mt = 0; mt < 2; ++mt)
#pragma unroll
        for (int nt = 0; nt < 4; ++nt) acc[mt][nt] = (f32x4){0.f, 0.f, 0.f, 0.f};

    const short8v zf = {0, 0, 0, 0, 0, 0, 0, 0};

#pragma unroll
    for (int di = 0; di < 3; ++di) {
#pragma unroll
        for (int dj = 0; dj < 3; ++dj) {
            const int tap = di * 3 + dj;
#pragma unroll
            for (int kk = 0; kk < 2; ++kk) {
                const int cc8 = (kk * 4 + sub) << 3;
                short8v a0 = *(const short8v*)(wofft + ((tap * 32 +      r16) << 6) + cc8);
                short8v a1 = *(const short8v*)(wofft + ((tap * 32 + 16 + r16) << 6) + cc8);
                short8v bfr[4];
#pragma unroll
                for (int nt = 0; nt < 4; ++nt) {
                    int ntile = wv * 4 + nt;
                    int y = r0 + (ntile >> 3) + di - 1;
                    int w = (ntile & 7) * 16 + r16 + dj - 1;
                    bool valid = (y >= 0 && y < Hn && w >= 0 && w < Wn);
                    int yc = valid ? y : 0, wc = valid ? w : 0;
                    short8v v = *(const short8v*)(xtb + (yc << 13) + (wc << 6) + cc8);
                    bfr[nt] = valid ? v : zf;
                }
#pragma unroll
                for (int nt = 0; nt < 4; ++nt) {
                    acc[0][nt] = __builtin_amdgcn_mfma_f32_16x16x32_bf16(a0, bfr[nt], acc[0][nt], 0, 0, 0);
                    acc[1][nt] = __builtin_amdgcn_mfma_f32_16x16x32_bf16(a1, bfr[nt], acc[1][nt], 0, 0, 0);
                }
            }
        }
    }

    // epilogue: D col=r16 (w), row=sub*4+r (ch); bias add; bf16 store
#pragma unroll
    for (int mt = 0; mt < 2; ++mt)
#pragma unroll
        for (int nt = 0; nt < 4; ++nt) {
            int ntile = wv * 4 + nt;
            int h = r0 + (ntile >> 3), w = (ntile & 7) * 16 + r16;
#pragma unroll
            for (int r = 0; r < 4; ++r) {
                int ch = mt * 16 + sub * 4 + r;
                if (ch < 27)
                    offo[(((long)(b * 27 + ch)) << 14) + (h << 7) + w] = f2bf(acc[mt][nt][r] + b_off[ch]);
            }
        }
}

// ---------------------------------------------------------------------------
// dcn_direct: deformable conv, zero LDS.  Each lane builds its MFMA B-frags
// in registers from 4 bilinear-corner 16B loads of xt (NHWC bf16); A-frags
// direct from w2.  Per-k bilinear params computed inline for 4 pos tiles.
// ---------------------------------------------------------------------------
__launch_bounds__(256)
__global__ void dcn_direct(const unsigned short* __restrict__ xt,
                           const unsigned short* __restrict__ offo,
                           const unsigned short* __restrict__ w2,
                           float* __restrict__ out) {
    int blk = blockIdx.x;
    blk = (blk & 7) * 128 + (blk >> 3);              // XCD swizzle: b = origBlk & 7
    const int b = blk >> 7, h = blk & 127;
    const int t = threadIdx.x;
    const int lane = t & 63, wv = t >> 6;
    const int ohalf = wv & 1, phalf = wv >> 1;
    const int r16 = lane & 15, sub = lane >> 4;
    const unsigned short* xtb = xt + ((long)b << 20);
    const unsigned short* ob  = offo + (((long)b * 27) << 14) + (h << 7);

    f32x4 acc[2][4];
#pragma unroll
    for (int ot = 0; ot < 2; ++ot)
#pragma unroll
        for (int pt = 0; pt < 4; ++pt)
            acc[ot][pt] = (f32x4){0.f, 0.f, 0.f, 0.f};

    for (int k = 0; k < KKn; ++k) {
        const int ky = k / 3 - 1, kx = k % 3 - 1;
        int o00[4], o01[4], o10[4], o11[4];
        float q00[4], q01[4], q10[4], q11[4];
#pragma unroll
        for (int pt = 0; pt < 4; ++pt) {
            int pos = phalf * 64 + pt * 16 + r16;
            float dy = bf2f(ob[((long)(2 * k) << 14) + pos]);
            float dx = bf2f(ob[((long)(2 * k + 1) << 14) + pos]);
            float m  = bf2f(ob[((long)(18 + k) << 14) + pos]);
            m = 1.f / (1.f + __expf(-m));
            float py = (float)(h + ky) + dy;
            float px = (float)(pos + kx) + dx;
            float fy = floorf(py), fx = floorf(px);
            int y0 = (int)fy, x0 = (int)fx;
            float wy1 = py - fy, wx1 = px - fx;
            float a0 = (y0 >= 0     && y0 < Hn)     ? (1.f - wy1) * m : 0.f;
            float a1 = (y0 + 1 >= 0 && y0 + 1 < Hn) ? wy1 * m         : 0.f;
            float b0 = (x0 >= 0     && x0 < Wn)     ? (1.f - wx1)     : 0.f;
            float b1 = (x0 + 1 >= 0 && x0 + 1 < Wn) ? wx1             : 0.f;
            q00[pt] = a0 * b0; q01[pt] = a0 * b1; q10[pt] = a1 * b0; q11[pt] = a1 * b1;
            int y0c = min(max(y0, 0), Hn - 1), y1c = min(max(y0 + 1, 0), Hn - 1);
            int x0c = min(max(x0, 0), Wn - 1), x1c = min(max(x0 + 1, 0), Wn - 1);
            o00[pt] = (y0c << 13) + (x0c << 6); o01[pt] = (y0c << 13) + (x1c << 6);
            o10[pt] = (y1c << 13) + (x0c << 6); o11[pt] = (y1c << 13) + (x1c << 6);
        }

#pragma unroll
        for (int kk = 0; kk < 2; ++kk) {
            const int cc8 = (kk * 4 + sub) << 3;
            short8v af[2];
            af[0] = *(const short8v*)(w2 + (k << 12) + ((ohalf * 32 +      r16) << 6) + cc8);
            af[1] = *(const short8v*)(w2 + (k << 12) + ((ohalf * 32 + 16 + r16) << 6) + cc8);
            short8v bfr[4];
#pragma unroll
            for (int pt = 0; pt < 4; ++pt) {
                short8v c00 = *(const short8v*)(xtb + o00[pt] + cc8);
                short8v c01 = *(const short8v*)(xtb + o01[pt] + cc8);
                short8v c10 = *(const short8v*)(xtb + o10[pt] + cc8);
                short8v c11 = *(const short8v*)(xtb + o11[pt] + cc8);
                const unsigned* u00 = (const unsigned*)&c00;
                const unsigned* u01 = (const unsigned*)&c01;
                const unsigned* u10 = (const unsigned*)&c10;
                const unsigned* u11 = (const unsigned*)&c11;
                short8v bf;
                unsigned* ub = (unsigned*)&bf;
#pragma unroll
                for (int jj = 0; jj < 4; ++jj) {
                    float f00l = __uint_as_float(u00[jj] << 16), f00h = __uint_as_float(u00[jj] & 0xffff0000u);
                    float f01l = __uint_as_float(u01[jj] << 16), f01h = __uint_as_float(u01[jj] & 0xffff0000u);
                    float f10l = __uint_as_float(u10[jj] << 16), f10h = __uint_as_float(u10[jj] & 0xffff0000u);
                    float f11l = __uint_as_float(u11[jj] << 16), f11h = __uint_as_float(u11[jj] & 0xffff0000u);
                    float tl = q00[pt] * f00l + q01[pt] * f01l + q10[pt] * f10l + q11[pt] * f11l;
                    float th = q00[pt] * f00h + q01[pt] * f01h + q10[pt] * f10h + q11[pt] * f11h;
                    ub[jj] = (unsigned)f2bf(tl) | ((unsigned)f2bf(th) << 16);
                }
                bfr[pt] = bf;
            }
#pragma unroll
            for (int ot = 0; ot < 2; ++ot)
#pragma unroll
                for (int pt = 0; pt < 4; ++pt)
                    acc[ot][pt] = __builtin_amdgcn_mfma_f32_16x16x32_bf16(af[ot], bfr[pt], acc[ot][pt], 0, 0, 0);
        }
    }

    // epilogue: D col=r16 (pos), row=sub*4+r (cout)
    const long obase = (((long)b * COUTn) << 14) + (h << 7);
#pragma unroll
    for (int ot = 0; ot < 2; ++ot)
#pragma unroll
        for (int pt = 0; pt < 4; ++pt) {
#pragma unroll
            for (int r = 0; r < 4; ++r) {
                int o   = ohalf * 32 + ot * 16 + sub * 4 + r;
                int pos = phalf * 64 + pt * 16 + r16;
                out[obase + ((long)o << 14) + pos] = acc[ot][pt][r];
            }
        }
}

// ---------------------------------------------------------------------------
extern "C" void kernel_launch(void* const* d_in, const int* in_sizes, int n_in,
                              void* d_out, int out_size, void* d_ws, size_t ws_size,
                              hipStream_t stream) {
    const float* x     = (const float*)d_in[0];
    const float* w_off = (const float*)d_in[1];
    const float* b_off = (const float*)d_in[2];
    const float* w_dcn = (const float*)d_in[3];
    float* out = (float*)d_out;

    unsigned short* xt    = (unsigned short*)d_ws;                      // 16777216 B
    unsigned short* w2    = (unsigned short*)((char*)d_ws + 16777216);  //    73728 B
    unsigned short* wofft = (unsigned short*)((char*)d_ws + 16850944);  //    36864 B
    unsigned short* offo  = (unsigned short*)((char*)d_ws + 16887808);  //  7077888 B

    xt_prep<<<Bn * Hn, 256, 0, stream>>>(x, xt);
    wdcn_prep<<<144, 256, 0, stream>>>(w_dcn, w2);
    woffprep<<<72, 256, 0, stream>>>(w_off, wofft);
    offconv_direct<<<512, 256, 0, stream>>>(xt, wofft, b_off, offo);
    dcn_direct<<<Bn * Hn, 256, 0, stream>>>(xt, offo, w2, out);
}

// Round 8
// 242.378 us; speedup vs baseline: 2.4526x; 1.0616x over previous
//
#include <hip/hip_runtime.h>

#define Bn 8
#define CINn 64
#define COUTn 64
#define Hn 128
#define Wn 128
#define KKn 9

typedef __attribute__((ext_vector_type(8))) short short8v;   // 8 bf16 (4 VGPR)
typedef __attribute__((ext_vector_type(4))) float f32x4;     // MFMA accumulator

__device__ __forceinline__ unsigned short f2bf(float f) {
    unsigned u = __float_as_uint(f);
    unsigned r = (u + 0x7FFFu + ((u >> 16) & 1u)) >> 16;     // RNE
    return (unsigned short)r;
}
__device__ __forceinline__ float bf2f(unsigned short u) {
    return __uint_as_float(((unsigned)u) << 16);
}

// ---------------------------------------------------------------------------
// xt_prep: x f32 NCHW -> xt bf16 NHWC  (xt[b][y][x][c], c contiguous)
// ---------------------------------------------------------------------------
__launch_bounds__(256)
__global__ void xt_prep(const float* __restrict__ x, unsigned short* __restrict__ xt) {
    __shared__ unsigned short tile[128 * 68];        // 17408 B
    const int blk = blockIdx.x;
    const int b = blk >> 7, y = blk & 127;
    const int t = threadIdx.x;
    const float* xb = x + (((long)b * CINn) << 14) + (y << 7);
#pragma unroll
    for (int i = 0; i < 32; ++i) {
        int e = i * 256 + t;                         // c = e>>7, xx = e&127
        int c = e >> 7, xx = e & 127;
        tile[xx * 68 + c] = f2bf(xb[((long)c << 14) + xx]);
    }
    __syncthreads();
    unsigned short* dst = xt + ((long)(b * 128 + y) << 13);
#pragma unroll
    for (int i = 0; i < 4; ++i) {
        int q = i * 256 + t;                         // 16B chunk: xx = q>>3, j = q&7
        int xx = q >> 3, j = q & 7;
        const unsigned long long* src = (const unsigned long long*)&tile[xx * 68 + j * 8];
        unsigned long long v0 = src[0], v1 = src[1];
        unsigned long long* d = (unsigned long long*)&dst[q * 8];
        d[0] = v0; d[1] = v1;
    }
}

// ---------------------------------------------------------------------------
// wdcn_prep: w_dcn (COUT, CIN, 3,3) -> bf16 w2[k][o][c]
// ---------------------------------------------------------------------------
__global__ void wdcn_prep(const float* __restrict__ w_dcn, unsigned short* __restrict__ w2) {
    int i = blockIdx.x * 256 + threadIdx.x;          // 36864 = [k][o][c]
    if (i >= COUTn * CINn * KKn) return;
    int c = i & 63;
    int o = (i >> 6) & 63;
    int k = i >> 12;
    w2[i] = f2bf(w_dcn[(o * CINn + c) * KKn + k]);
}

// ---------------------------------------------------------------------------
// woffprep: w_off (27, 64, 3,3) -> bf16 wofft[tap][ch pad32][c]  (zeros ch>=27)
// ---------------------------------------------------------------------------
__global__ void woffprep(const float* __restrict__ w_off, unsigned short* __restrict__ wofft) {
    int i = blockIdx.x * 256 + threadIdx.x;          // 18432 = [tap][ch][c]
    if (i >= 9 * 32 * 64) return;
    int c   = i & 63;
    int ch  = (i >> 6) & 31;
    int tap = i >> 11;
    wofft[i] = (ch < 27) ? f2bf(w_off[(ch * 64 + c) * 9 + tap]) : (unsigned short)0;
}

// ---------------------------------------------------------------------------
// offconv_direct: off via MFMA, zero LDS.  Block = (b, h): one row, 128 pos.
// Wave wv owns pos [wv*32, wv*32+32) x both ch-tiles -> no duplicated B work,
// 1024 blocks (4/CU).  B-frags straight from xt (NHWC); OOB taps -> zero.
// Output off stored bf16 planar [b][27][h][w].
// ---------------------------------------------------------------------------
__launch_bounds__(256)
__global__ void offconv_direct(const unsigned short* __restrict__ xt,
                               const unsigned short* __restrict__ wofft,
                               const float* __restrict__ b_off,
                               unsigned short* __restrict__ offo) {
    int blk = blockIdx.x;
    blk = (blk & 7) * 128 + (blk >> 3);              // XCD swizzle: b = origBlk & 7
    const int b = blk >> 7, h = blk & 127;
    const int t = threadIdx.x;
    const int lane = t & 63, wv = t >> 6;
    const int r16 = lane & 15, sub = lane >> 4;
    const unsigned short* xtb = xt + ((long)b << 20);

    f32x4 acc[2][2];
#pragma unroll
    for (int mt = 0; mt < 2; ++mt)
#pragma unroll
        for (int ntl = 0; ntl < 2; ++ntl) acc[mt][ntl] = (f32x4){0.f, 0.f, 0.f, 0.f};

    const short8v zf = {0, 0, 0, 0, 0, 0, 0, 0};

#pragma unroll
    for (int di = 0; di < 3; ++di) {
        const int y = h + di - 1;
        const bool yok = (y >= 0 && y < Hn);
#pragma unroll
        for (int dj = 0; dj < 3; ++dj) {
            const int tap = di * 3 + dj;
#pragma unroll
            for (int kk = 0; kk < 2; ++kk) {
                const int cc8 = (kk * 4 + sub) << 3;
                short8v a0 = *(const short8v*)(wofft + ((tap * 32 +      r16) << 6) + cc8);
                short8v a1 = *(const short8v*)(wofft + ((tap * 32 + 16 + r16) << 6) + cc8);
                short8v bfr[2];
#pragma unroll
                for (int ntl = 0; ntl < 2; ++ntl) {
                    int w = wv * 32 + ntl * 16 + r16 + dj - 1;
                    bool valid = yok && (w >= 0 && w < Wn);
                    int wc = valid ? w : 0;
                    int yc = yok ? y : 0;
                    short8v v = *(const short8v*)(xtb + (yc << 13) + (wc << 6) + cc8);
                    bfr[ntl] = valid ? v : zf;
                }
#pragma unroll
                for (int ntl = 0; ntl < 2; ++ntl) {
                    acc[0][ntl] = __builtin_amdgcn_mfma_f32_16x16x32_bf16(a0, bfr[ntl], acc[0][ntl], 0, 0, 0);
                    acc[1][ntl] = __builtin_amdgcn_mfma_f32_16x16x32_bf16(a1, bfr[ntl], acc[1][ntl], 0, 0, 0);
                }
            }
        }
    }

    // epilogue: D col=r16 (w), row=sub*4+r (ch); bias add; bf16 store
#pragma unroll
    for (int mt = 0; mt < 2; ++mt)
#pragma unroll
        for (int ntl = 0; ntl < 2; ++ntl) {
            int w = wv * 32 + ntl * 16 + r16;
#pragma unroll
            for (int r = 0; r < 4; ++r) {
                int ch = mt * 16 + sub * 4 + r;
                if (ch < 27)
                    offo[(((long)(b * 27 + ch)) << 14) + (h << 7) + w] = f2bf(acc[mt][ntl][r] + b_off[ch]);
            }
        }
}

// ---------------------------------------------------------------------------
// dcn_direct: deformable conv, zero LDS, dedup mapping.  Wave wv owns pos
// [wv*32, wv*32+32) x ALL 4 cout tiles: each B-frag built once per block and
// feeds 4 MFMAs.  Corner loads 16B from xt (NHWC bf16); A-frags wave-uniform.
// ---------------------------------------------------------------------------
__launch_bounds__(256)
__global__ void dcn_direct(const unsigned short* __restrict__ xt,
                           const unsigned short* __restrict__ offo,
                           const unsigned short* __restrict__ w2,
                           float* __restrict__ out) {
    int blk = blockIdx.x;
    blk = (blk & 7) * 128 + (blk >> 3);              // XCD swizzle: b = origBlk & 7
    const int b = blk >> 7, h = blk & 127;
    const int t = threadIdx.x;
    const int lane = t & 63, wv = t >> 6;
    const int r16 = lane & 15, sub = lane >> 4;
    const unsigned short* xtb = xt + ((long)b << 20);
    const unsigned short* ob  = offo + (((long)b * 27) << 14) + (h << 7);

    f32x4 acc[4][2];
#pragma unroll
    for (int ot = 0; ot < 4; ++ot)
#pragma unroll
        for (int ptl = 0; ptl < 2; ++ptl)
            acc[ot][ptl] = (f32x4){0.f, 0.f, 0.f, 0.f};

    for (int k = 0; k < KKn; ++k) {
        const int ky = k / 3 - 1, kx = k % 3 - 1;
        int o00[2], o01[2], o10[2], o11[2];
        float q00[2], q01[2], q10[2], q11[2];
#pragma unroll
        for (int ptl = 0; ptl < 2; ++ptl) {
            int pos = wv * 32 + ptl * 16 + r16;
            float dy = bf2f(ob[((long)(2 * k) << 14) + pos]);
            float dx = bf2f(ob[((long)(2 * k + 1) << 14) + pos]);
            float m  = bf2f(ob[((long)(18 + k) << 14) + pos]);
            m = 1.f / (1.f + __expf(-m));
            float py = (float)(h + ky) + dy;
            float px = (float)(pos + kx) + dx;
            float fy = floorf(py), fx = floorf(px);
            int y0 = (int)fy, x0 = (int)fx;
            float wy1 = py - fy, wx1 = px - fx;
            float a0 = (y0 >= 0     && y0 < Hn)     ? (1.f - wy1) * m : 0.f;
            float a1 = (y0 + 1 >= 0 && y0 + 1 < Hn) ? wy1 * m         : 0.f;
            float b0 = (x0 >= 0     && x0 < Wn)     ? (1.f - wx1)     : 0.f;
            float b1 = (x0 + 1 >= 0 && x0 + 1 < Wn) ? wx1             : 0.f;
            q00[ptl] = a0 * b0; q01[ptl] = a0 * b1; q10[ptl] = a1 * b0; q11[ptl] = a1 * b1;
            int y0c = min(max(y0, 0), Hn - 1), y1c = min(max(y0 + 1, 0), Hn - 1);
            int x0c = min(max(x0, 0), Wn - 1), x1c = min(max(x0 + 1, 0), Wn - 1);
            o00[ptl] = (y0c << 13) + (x0c << 6); o01[ptl] = (y0c << 13) + (x1c << 6);
            o10[ptl] = (y1c << 13) + (x0c << 6); o11[ptl] = (y1c << 13) + (x1c << 6);
        }

#pragma unroll
        for (int kk = 0; kk < 2; ++kk) {
            const int cc8 = (kk * 4 + sub) << 3;
            short8v af[4];
#pragma unroll
            for (int ot = 0; ot < 4; ++ot)
                af[ot] = *(const short8v*)(w2 + (k << 12) + ((ot * 16 + r16) << 6) + cc8);
            short8v bfr[2];
#pragma unroll
            for (int ptl = 0; ptl < 2; ++ptl) {
                short8v c00 = *(const short8v*)(xtb + o00[ptl] + cc8);
                short8v c01 = *(const short8v*)(xtb + o01[ptl] + cc8);
                short8v c10 = *(const short8v*)(xtb + o10[ptl] + cc8);
                short8v c11 = *(const short8v*)(xtb + o11[ptl] + cc8);
                const unsigned* u00 = (const unsigned*)&c00;
                const unsigned* u01 = (const unsigned*)&c01;
                const unsigned* u10 = (const unsigned*)&c10;
                const unsigned* u11 = (const unsigned*)&c11;
                short8v bf;
                unsigned* ub = (unsigned*)&bf;
#pragma unroll
                for (int jj = 0; jj < 4; ++jj) {
                    float f00l = __uint_as_float(u00[jj] << 16), f00h = __uint_as_float(u00[jj] & 0xffff0000u);
                    float f01l = __uint_as_float(u01[jj] << 16), f01h = __uint_as_float(u01[jj] & 0xffff0000u);
                    float f10l = __uint_as_float(u10[jj] << 16), f10h = __uint_as_float(u10[jj] & 0xffff0000u);
                    float f11l = __uint_as_float(u11[jj] << 16), f11h = __uint_as_float(u11[jj] & 0xffff0000u);
                    float tl = q00[ptl] * f00l + q01[ptl] * f01l + q10[ptl] * f10l + q11[ptl] * f11l;
                    float th = q00[ptl] * f00h + q01[ptl] * f01h + q10[ptl] * f10h + q11[ptl] * f11h;
                    ub[jj] = (unsigned)f2bf(tl) | ((unsigned)f2bf(th) << 16);
                }
                bfr[ptl] = bf;
            }
#pragma unroll
            for (int ot = 0; ot < 4; ++ot)
#pragma unroll
                for (int ptl = 0; ptl < 2; ++ptl)
                    acc[ot][ptl] = __builtin_amdgcn_mfma_f32_16x16x32_bf16(af[ot], bfr[ptl], acc[ot][ptl], 0, 0, 0);
        }
    }

    // epilogue: D col=r16 (pos), row=sub*4+r (cout)
    const long obase = (((long)b * COUTn) << 14) + (h << 7);
#pragma unroll
    for (int ot = 0; ot < 4; ++ot)
#pragma unroll
        for (int ptl = 0; ptl < 2; ++ptl) {
#pragma unroll
            for (int r = 0; r < 4; ++r) {
                int o   = ot * 16 + sub * 4 + r;
                int pos = wv * 32 + ptl * 16 + r16;
                out[obase + ((long)o << 14) + pos] = acc[ot][ptl][r];
            }
        }
}

// ---------------------------------------------------------------------------
extern "C" void kernel_launch(void* const* d_in, const int* in_sizes, int n_in,
                              void* d_out, int out_size, void* d_ws, size_t ws_size,
                              hipStream_t stream) {
    const float* x     = (const float*)d_in[0];
    const float* w_off = (const float*)d_in[1];
    const float* b_off = (const float*)d_in[2];
    const float* w_dcn = (const float*)d_in[3];
    float* out = (float*)d_out;

    unsigned short* xt    = (unsigned short*)d_ws;                      // 16777216 B
    unsigned short* w2    = (unsigned short*)((char*)d_ws + 16777216);  //    73728 B
    unsigned short* wofft = (unsigned short*)((char*)d_ws + 16850944);  //    36864 B
    unsigned short* offo  = (unsigned short*)((char*)d_ws + 16887808);  //  7077888 B

    xt_prep<<<Bn * Hn, 256, 0, stream>>>(x, xt);
    wdcn_prep<<<144, 256, 0, stream>>>(w_dcn, w2);
    woffprep<<<72, 256, 0, stream>>>(w_off, wofft);
    offconv_direct<<<Bn * Hn, 256, 0, stream>>>(xt, wofft, b_off, offo);
    dcn_direct<<<Bn * Hn, 256, 0, stream>>>(xt, offo, w2, out);
}